// Round 9
// baseline (283.146 us; speedup 1.0000x reference)
//
#include <hip/hip_runtime.h>
#include <cmath>

#define BB 32     // batch
#define NN 784    // full points (28*28)
#define MM 392    // downsampled points (::2)
#define DD 1024   // feature dim
#define CC 20     // classes
#define JJ 3      // k-means centroids per class (K-1)
#define KP 4      // protos per class (3 centroids + backbone)
#define KM_ITERS 10
#define GMAX 64   // max members per (b,c); binomial(392,1/20) => P(>64) ~ 1e-16
#define NCOL (BB * CC * KP)   // 2560 proto columns
#define NQ0B 98   // q0h blocks (8 rows each, 784 rows)
#define NTSB (BB * 16)        // totalsum blocks

typedef __attribute__((ext_vector_type(8))) short bf16x8;
typedef __attribute__((ext_vector_type(4))) float f32x4;

// ---- bf16 split helpers (RTN-even) ----
__device__ inline unsigned short f2bf(float x) {
  unsigned int u = __float_as_uint(x);
  u += 0x7FFFu + ((u >> 16) & 1u);
  return (unsigned short)(u >> 16);
}
__device__ inline float bf2f(unsigned short h) {
  return __uint_as_float(((unsigned int)h) << 16);
}
__device__ inline void f2bf2(float x, unsigned short& hi, unsigned short& lo) {
  hi = f2bf(x);
  lo = f2bf(x - bf2f(hi));
}
__device__ inline void store_bf4(unsigned short* baseh, unsigned short* basel,
                                 int idx4, float4 v) {
  ushort4 h, l;
  f2bf2(v.x, h.x, l.x); f2bf2(v.y, h.y, l.y);
  f2bf2(v.z, h.z, l.z); f2bf2(v.w, h.w, l.w);
  ((ushort4*)baseh)[idx4] = h;
  ((ushort4*)basel)[idx4] = l;
}
// 8 fp32 -> bf16x8 hi + bf16x8 lo (all constant-indexed -> registers)
__device__ inline void cvt8(const float4& x0, const float4& x1, bf16x8& h8, bf16x8& l8) {
  float xs[8] = {x0.x, x0.y, x0.z, x0.w, x1.x, x1.y, x1.z, x1.w};
  bf16x8 h, l;
  #pragma unroll
  for (int i = 0; i < 8; i++) {
    unsigned short hi, lo;
    f2bf2(xs[i], hi, lo);
    h[i] = (short)hi; l[i] = (short)lo;
  }
  h8 = h; l8 = l;
}

// ---------- fused prep: heterogeneous grid ----------
__global__ __launch_bounds__(512) void k_prep(
    const float* __restrict__ score, const float* __restrict__ query,
    const int* __restrict__ label,
    int* __restrict__ cls, float* __restrict__ sm, int* __restrict__ valid,
    float* __restrict__ totalsum,
    unsigned short* __restrict__ q0hh, unsigned short* __restrict__ q0hl,
    float* __restrict__ gred, float* __restrict__ zbuf) {
  int blk = blockIdx.x;
  int tid = threadIdx.x, lane = tid & 63, wv = tid >> 6;
  __shared__ int s_cnt[CC];
  __shared__ float sa[8][64];

  if (blk < BB) {
    int b = blk;
    if (tid < CC) s_cnt[tid] = 0;
    __syncthreads();
    if (tid < MM) {
      const float4* s4 = (const float4*)(score + ((size_t)b * NN + 2 * tid) * CC);
      float4 r[5];
      #pragma unroll
      for (int k = 0; k < 5; k++) r[k] = s4[k];
      const float* s = (const float*)r;
      float best = s[0]; int bi = 0; float acc = s[0];
      #pragma unroll
      for (int c = 1; c < CC; c++) { float v = s[c]; acc += v; if (v > best) { best = v; bi = c; } }
      cls[b * MM + tid] = bi;
      sm[b * MM + tid] = acc / (float)CC;
      atomicAdd(&s_cnt[bi], 1);
    }
    __syncthreads();
    if (tid < CC) {
      int cv = s_cnt[tid];
      valid[b * CC + tid] = (label[b * CC + tid] > 0 && cv >= KP) ? 1 : 0;
    }
    if (blk == 0) {
      if (tid == 0) { gred[0] = 0.f; gred[1] = 0.f; ((int*)gred)[2] = 0; }
      zbuf[tid] = 0.f; zbuf[tid + 512] = 0.f;     // zero row for k_gram padding
    }
  } else if (blk < BB + NQ0B) {
    int n = (blk - BB) * 8 + wv;             // 0..783
    const float* src = query + (size_t)n * DD;
    float v[16];
    float ss = 0.f;
    #pragma unroll
    for (int j = 0; j < 16; j++) { v[j] = src[lane + 64 * j]; ss += v[j] * v[j]; }
    #pragma unroll
    for (int o = 32; o > 0; o >>= 1) ss += __shfl_xor(ss, o, 64);
    float nrm = fmaxf(sqrtf(ss), 1e-12f);
    #pragma unroll
    for (int j = 0; j < 16; j++) {
      unsigned short hi, lo;
      f2bf2(v[j] / nrm, hi, lo);
      q0hh[(size_t)n * DD + lane + 64 * j] = hi;
      q0hl[(size_t)n * DD + lane + 64 * j] = lo;
    }
  } else {
    int t = blk - BB - NQ0B;                 // 0..511
    int b = t >> 4, ch = t & 15;
    const float* qb = query + (size_t)b * NN * DD + ch * 64 + lane;
    float a = 0.f;
    #pragma unroll 7
    for (int r = 0; r < 49; r++) {
      int i = wv * 49 + r;
      a += qb[(size_t)(2 * i) * DD];         // coalesced 256B per row
    }
    sa[wv][lane] = a;
    __syncthreads();
    if (wv == 0) {
      float s = 0.f;
      #pragma unroll
      for (int w = 0; w < 8; w++) s += sa[w][lane];
      totalsum[(size_t)b * DD + ch * 64 + lane] = s;
    }
  }
}

// ---------- fused (valid blocks only): membership + direct-global MFMA-Gram + k-means + protos ----------
// Gram fragments read STRAIGHT FROM GLOBAL (L2-hot rows), converted to bf16 hi/lo in-register:
// no LDS staging, no per-chunk barriers (3 barriers total), LDS 17.7 KB -> 4 blocks/CU.
// Padding rows (>= mc) point at zbuf (zeros) so they contribute 0 to G.
__global__ __launch_bounds__(512) void k_gram(
    const float* __restrict__ query, const int* __restrict__ cls,
    const int* __restrict__ valid, const float* __restrict__ sm,
    const float* __restrict__ totalsum, const float* __restrict__ zbuf,
    unsigned short* __restrict__ phh, unsigned short* __restrict__ phl) {
  int bc = blockIdx.x;
  if (!valid[bc]) return;              // invalid pairs: no work at all
  int b = bc / CC, c = bc - b * CC;
  int tid = threadIdx.x, lane = tid & 63, wv = tid >> 6;
  const float* qb = query + (size_t)b * NN * DD;
  __shared__ int s_wtot[8];
  __shared__ int s_list[GMAX];
  __shared__ float Gl[GMAX][65];       // 16.6 KB Gram
  __shared__ float s_w[JJ][GMAX];
  __shared__ int s_rank[JJ];
  __shared__ float s_red2[8];

  // ---- membership via ballot scan (stable ascending i), 2 barriers
  int flag = 0;
  if (tid < MM) flag = (cls[b * MM + tid] == c) ? 1 : 0;
  unsigned long long msk = __ballot(flag);
  int wp = __popcll(msk & ((1ull << lane) - 1ull));
  if (lane == 0) s_wtot[wv] = __popcll(msk);
  __syncthreads();
  int off = 0, mtot = 0;
  #pragma unroll
  for (int w = 0; w < 8; w++) { int t = s_wtot[w]; if (w < wv) off += t; mtot += t; }
  int mc = mtot > GMAX ? GMAX : mtot;
  if (flag) { int pos = off + wp; if (pos < GMAX) s_list[pos] = tid; }
  __syncthreads();                     // s_list visible

  int T16 = (mc + 15) >> 4;            // 16-row tiles covering mc
  int ntile16 = T16 * (T16 + 1) / 2;   // <= 10 upper-triangle G tiles
  int fr = lane & 15, fkq = lane >> 4; // fragment: row fr, k-offset fkq*8

  // ---- this wave's tiles (t = wv, wv+8); fragment pointers into global (or zbuf)
  int tis[2], tjs[2];
  const float* pA[2]; const float* pB[2];
  f32x4 accs[2];
  #pragma unroll
  for (int tt = 0; tt < 2; tt++) {
    accs[tt] = (f32x4){0.f, 0.f, 0.f, 0.f};
    tis[tt] = -1; tjs[tt] = 0; pA[tt] = zbuf; pB[tt] = zbuf;
    int t = wv + 8 * tt;
    if (t < ntile16) {
      int i = 0;
      while ((i + 1) * (i + 2) / 2 <= t) i++;
      tis[tt] = i; tjs[tt] = t - i * (i + 1) / 2;
      int ra = 16 * tis[tt] + fr, rb = 16 * tjs[tt] + fr;
      pA[tt] = (ra < mc) ? qb + (size_t)(2 * s_list[ra]) * DD + fkq * 8 : zbuf + fkq * 8;
      pB[tt] = (rb < mc) ? qb + (size_t)(2 * s_list[rb]) * DD + fkq * 8 : zbuf + fkq * 8;
    }
  }

  // ---- Gram: 32 k-steps, 3 split-MFMA per tile per step, zero barriers
  for (int ks = 0; ks < 32; ks++) {
    #pragma unroll
    for (int tt = 0; tt < 2; tt++) {
      if (tis[tt] >= 0) {
        float4 a0 = *(const float4*)(pA[tt] + 32 * ks);
        float4 a1 = *(const float4*)(pA[tt] + 32 * ks + 4);
        float4 b0 = *(const float4*)(pB[tt] + 32 * ks);
        float4 b1 = *(const float4*)(pB[tt] + 32 * ks + 4);
        bf16x8 ah, al, bh, bl;
        cvt8(a0, a1, ah, al);
        cvt8(b0, b1, bh, bl);
        accs[tt] = __builtin_amdgcn_mfma_f32_16x16x32_bf16(ah, bh, accs[tt], 0, 0, 0);
        accs[tt] = __builtin_amdgcn_mfma_f32_16x16x32_bf16(ah, bl, accs[tt], 0, 0, 0);
        accs[tt] = __builtin_amdgcn_mfma_f32_16x16x32_bf16(al, bh, accs[tt], 0, 0, 0);
      }
    }
  }

  // ---- write G tiles (C/D layout: col=lane&15 (B-side), row=(lane>>4)*4+reg (A-side)) + mirror
  #pragma unroll
  for (int tt = 0; tt < 2; tt++) {
    if (tis[tt] >= 0) {
      #pragma unroll
      for (int r = 0; r < 4; r++) {
        int gr = 16 * tis[tt] + fkq * 4 + r;
        int gc = 16 * tjs[tt] + fr;
        Gl[gr][gc] = accs[tt][r]; Gl[gc][gr] = accs[tt][r];
      }
    }
  }
  __syncthreads();

  // ---- Gram-space k-means: wave 0 only (in-wave LDS ordering; no barriers needed)
  if (wv == 0) {
    bool act = lane < mc;
    float smv = act ? sm[b * MM + s_list[lane]] : 0.f;
    s_w[0][lane] = (lane == 0) ? 1.f : 0.f;
    s_w[1][lane] = (lane == 1) ? 1.f : 0.f;
    s_w[2][lane] = (lane == 2) ? 1.f : 0.f;
    int aj = 0, n0 = 0, n1 = 0, n2 = 0;
    for (int it = 0; it <= KM_ITERS; it++) {
      float h0 = 0.f, h1 = 0.f, h2 = 0.f;
      if (act) {
        for (int i = 0; i < mc; i++) {
          float g = Gl[lane][i];
          h0 += s_w[0][i] * g; h1 += s_w[1][i] * g; h2 += s_w[2][i] * g;
        }
      }
      float t0 = s_w[0][lane] * h0, t1 = s_w[1][lane] * h1, t2 = s_w[2][lane] * h2;
      for (int o = 1; o < 64; o <<= 1) {
        t0 += __shfl_xor(t0, o, 64); t1 += __shfl_xor(t1, o, 64); t2 += __shfl_xor(t2, o, 64);
      }
      float e0 = t0 - 2.f * h0, e1 = t1 - 2.f * h1, e2 = t2 - 2.f * h2;
      aj = 0; float bv = e0;
      if (e1 < bv) { bv = e1; aj = 1; }
      if (e2 < bv) { bv = e2; aj = 2; }
      n0 = __popcll(__ballot(act && aj == 0));
      n1 = __popcll(__ballot(act && aj == 1));
      n2 = __popcll(__ballot(act && aj == 2));
      if (it == KM_ITERS) break;
      if (act) {                           // empty cluster keeps old w
        if (n0 > 0) s_w[0][lane] = (aj == 0) ? 1.f / (float)n0 : 0.f;
        if (n1 > 0) s_w[1][lane] = (aj == 1) ? 1.f / (float)n1 : 0.f;
        if (n2 > 0) s_w[2][lane] = (aj == 2) ? 1.f / (float)n2 : 0.f;
      }
    }
    float s0 = (act && aj == 0) ? smv : 0.f;
    float s1 = (act && aj == 1) ? smv : 0.f;
    float s2 = (act && aj == 2) ? smv : 0.f;
    for (int o = 1; o < 64; o <<= 1) {
      s0 += __shfl_xor(s0, o, 64); s1 += __shfl_xor(s1, o, 64); s2 += __shfl_xor(s2, o, 64);
    }
    if (lane == 0) {
      float avg[JJ];
      avg[0] = (n0 > 0) ? s0 / (float)n0 : -INFINITY;
      avg[1] = (n1 > 0) ? s1 / (float)n1 : -INFINITY;
      avg[2] = (n2 > 0) ? s2 / (float)n2 : -INFINITY;
      bool used[JJ] = {false, false, false};
      for (int s = 0; s < JJ; s++) {       // stable argsort descending
        int bi = -1; float bv = 0.f;
        for (int j = 0; j < JJ; j++)
          if (!used[j] && (bi < 0 || avg[j] > bv)) { bi = j; bv = avg[j]; }
        used[bi] = true; s_rank[bi] = s;   // rank of original cluster bi
      }
    }
  }
  __syncthreads();

  // ---- epilogue: 4 groups x 128 threads; j<3 = centroid j (unconditional FMA so the
  //      g-loop pipelines; w==0 rows contribute 0), j==3 = backbone.
  float4 a0 = make_float4(0.f, 0.f, 0.f, 0.f), a1 = make_float4(0.f, 0.f, 0.f, 0.f);
  int j = tid >> 7, q = tid & 127;
  if (j < 3) {
    for (int g = 0; g < mc; g++) {
      float w = s_w[j][g];                 // wave-uniform broadcast
      const float4* row = (const float4*)(qb + (size_t)(2 * s_list[g]) * DD);
      float4 v0 = row[q], v1 = row[q + 128];
      a0.x += w * v0.x; a0.y += w * v0.y; a0.z += w * v0.z; a0.w += w * v0.w;
      a1.x += w * v1.x; a1.y += w * v1.y; a1.z += w * v1.z; a1.w += w * v1.w;
    }
  } else {
    for (int g = 0; g < mc; g++) {
      const float4* row = (const float4*)(qb + (size_t)(2 * s_list[g]) * DD);
      float4 v0 = row[q], v1 = row[q + 128];
      a0.x += v0.x; a0.y += v0.y; a0.z += v0.z; a0.w += v0.w;
      a1.x += v1.x; a1.y += v1.y; a1.z += v1.z; a1.w += v1.w;
    }
    const float4* tb = (const float4*)(totalsum + (size_t)b * DD);
    float4 t0 = tb[q], t1 = tb[q + 128];
    float denom = fmaxf((float)(MM - mtot), 1.f);
    float inv = 1.f / denom;
    a0.x = (t0.x - a0.x) * inv; a0.y = (t0.y - a0.y) * inv;
    a0.z = (t0.z - a0.z) * inv; a0.w = (t0.w - a0.w) * inv;
    a1.x = (t1.x - a1.x) * inv; a1.y = (t1.y - a1.y) * inv;
    a1.z = (t1.z - a1.z) * inv; a1.w = (t1.w - a1.w) * inv;
  }
  float ssq = a0.x * a0.x + a0.y * a0.y + a0.z * a0.z + a0.w * a0.w
            + a1.x * a1.x + a1.y * a1.y + a1.z * a1.z + a1.w * a1.w;
  #pragma unroll
  for (int o = 1; o < 64; o <<= 1) ssq += __shfl_xor(ssq, o, 64);
  if (lane == 0) s_red2[wv] = ssq;
  __syncthreads();
  float nrm = fmaxf(sqrtf(s_red2[2 * j] + s_red2[2 * j + 1]), 1e-12f);
  int prow = (j < 3) ? s_rank[j] : 3;
  size_t rowoff = ((size_t)bc * KP + prow) * DD;
  float4 o0 = make_float4(a0.x / nrm, a0.y / nrm, a0.z / nrm, a0.w / nrm);
  float4 o1 = make_float4(a1.x / nrm, a1.y / nrm, a1.z / nrm, a1.w / nrm);
  store_bf4(phh + rowoff, phl + rowoff, q, o0);
  store_bf4(phh + rowoff, phl + rowoff, q + 128, o1);
}

// ---------- sim GEMM via bf16 split MFMA; 1 wave/block, 64x64 tile, no LDS, no barriers ----------
__global__ __launch_bounds__(64) void k_gemm(
    const unsigned short* __restrict__ Ah, const unsigned short* __restrict__ Al,
    const unsigned short* __restrict__ Bh, const unsigned short* __restrict__ Bl,
    float* __restrict__ P) {
  int n0 = blockIdx.y * 64;
  int m0 = blockIdx.x * 64;
  int lane = threadIdx.x;
  int kh = lane >> 4;                    // 0..3
  int lr = lane & 15;

  const unsigned short* pa_h[4]; const unsigned short* pa_l[4];
  #pragma unroll
  for (int mi = 0; mi < 4; mi++) {
    size_t o = (size_t)(m0 + mi * 16 + lr) * DD + kh * 8;   // OOB m-rows read adjacent ws (harmless, unstored)
    pa_h[mi] = Ah + o; pa_l[mi] = Al + o;
  }
  const unsigned short* pb_h[4]; const unsigned short* pb_l[4];
  #pragma unroll
  for (int ni = 0; ni < 4; ni++) {
    int col = n0 + ni * 16 + lr;         // B row == col (ph rows are [bc*KP+proto] = col order)
    size_t o = (size_t)col * DD + kh * 8;
    pb_h[ni] = Bh + o; pb_l[ni] = Bl + o;
  }

  f32x4 acc[4][4];
  #pragma unroll
  for (int mi = 0; mi < 4; mi++)
    #pragma unroll
    for (int ni = 0; ni < 4; ni++) acc[mi][ni] = (f32x4){0.f, 0.f, 0.f, 0.f};

  for (int k0 = 0; k0 < DD; k0 += 32) {
    bf16x8 ah[4], al[4], bh[4], bl[4];
    #pragma unroll
    for (int i = 0; i < 4; i++) {
      ah[i] = *(const bf16x8*)(pa_h[i] + k0);
      al[i] = *(const bf16x8*)(pa_l[i] + k0);
      bh[i] = *(const bf16x8*)(pb_h[i] + k0);
      bl[i] = *(const bf16x8*)(pb_l[i] + k0);
    }
    #pragma unroll
    for (int mi = 0; mi < 4; mi++)
      #pragma unroll
      for (int ni = 0; ni < 4; ni++) {
        acc[mi][ni] = __builtin_amdgcn_mfma_f32_16x16x32_bf16(ah[mi], bh[ni], acc[mi][ni], 0, 0, 0);
        acc[mi][ni] = __builtin_amdgcn_mfma_f32_16x16x32_bf16(ah[mi], bl[ni], acc[mi][ni], 0, 0, 0);
        acc[mi][ni] = __builtin_amdgcn_mfma_f32_16x16x32_bf16(al[mi], bh[ni], acc[mi][ni], 0, 0, 0);
      }
  }

  // C/D layout: col = lane&15, row = (lane>>4)*4 + reg  -> float4 contiguous in m
  #pragma unroll
  for (int ni = 0; ni < 4; ni++) {
    int col = n0 + ni * 16 + lr;
    #pragma unroll
    for (int mi = 0; mi < 4; mi++) {
      int m = m0 + mi * 16 + kh * 4;
      if (m < NN) {
        *(f32x4*)(P + (size_t)col * NN + m) = acc[mi][ni];
      }
    }
  }
}

// ---------- Sinkhorn + BCE: ONE WAVE per (b,c), one block per wave for full-CU spread ----------
__global__ __launch_bounds__(64) void k_sink(const float* __restrict__ P,
    const int* __restrict__ valid, const int* __restrict__ gt,
    const float* __restrict__ wts, float* __restrict__ gred, float* __restrict__ out) {
  int lane = threadIdx.x;
  int bc = blockIdx.x;
  int b = bc / CC, c = bc - b * CC;
  float bce_out = 0.f; int vld_out = 0;

  if (valid[bc]) {                         // wave-uniform
    float4 kv[13]; float rr[13];
    #pragma unroll
    for (int s = 0; s < 13; s++) {
      int n = lane + 64 * s;
      kv[s] = make_float4(0.f, 0.f, 0.f, 0.f); rr[s] = 1.f;
      if (n < NN) {
        float4 o;
        o.x = expf(-(1.0f - P[((size_t)(4 * bc + 0)) * NN + n]) / 0.1f);
        o.y = expf(-(1.0f - P[((size_t)(4 * bc + 1)) * NN + n]) / 0.1f);
        o.z = expf(-(1.0f - P[((size_t)(4 * bc + 2)) * NN + n]) / 0.1f);
        o.w = expf(-(1.0f - P[((size_t)(4 * bc + 3)) * NN + n]) / 0.1f);
        kv[s] = o;
      }
    }
    const float uu = 1.0f / (float)NN, vv = 1.0f / (float)KP;
    float c0 = 1.f, c1 = 1.f, c2 = 1.f, c3 = 1.f;
    for (int it = 0; it < 100; it++) {
      float dsum = 0.f, p0 = 0.f, p1 = 0.f, p2 = 0.f, p3 = 0.f;
      #pragma unroll
      for (int s = 0; s < 13; s++) {
        int n = lane + 64 * s;
        if (n < NN) {
          float4 k4 = kv[s];
          float S = k4.x * c0 + k4.y * c1 + k4.z * c2 + k4.w * c3;
          float r1 = uu / S;
          dsum += fabsf(r1 - rr[s]);
          rr[s] = r1;
          p0 += k4.x * r1; p1 += k4.y * r1; p2 += k4.z * r1; p3 += k4.w * r1;
        }
      }
      #pragma unroll
      for (int o = 1; o < 64; o <<= 1) {
        dsum += __shfl_xor(dsum, o, 64);
        p0 += __shfl_xor(p0, o, 64); p1 += __shfl_xor(p1, o, 64);
        p2 += __shfl_xor(p2, o, 64); p3 += __shfl_xor(p3, o, 64);
      }
      c0 = vv / p0; c1 = vv / p1; c2 = vv / p2; c3 = vv / p3;
      if (dsum / (float)NN < 0.01f) break;   // wave-uniform
    }
    float w0 = wts[0], w1 = wts[1], w2 = wts[2], w3 = wts[3];
    float bsum = 0.f; int nanloc = 0;
    const int* gtb = gt + b * NN;
    #pragma unroll
    for (int s = 0; s < 13; s++) {
      int n = lane + 64 * s;
      if (n < NN) {
        float4 k4 = kv[s];
        float rv = rr[s];
        float T0 = rv * c0 * k4.x, T1 = rv * c1 * k4.y, T2 = rv * c2 * k4.z, T3 = rv * c3 * k4.w;
        if (T0 != T0 || T1 != T1 || T2 != T2 || T3 != T3) nanloc = 1;
        float pred = T0 * w0 + T1 * w1 + T2 * w2 + T3 * w3;
        float pcl = fminf(fmaxf(pred, 0.f), 1.f);
        float t = (gtb[n] == c + 1) ? fmaxf(logf(pcl), -100.f) : fmaxf(logf(1.f - pcl), -100.f);
        bsum += t;
      }
    }
    #pragma unroll
    for (int o = 1; o < 64; o <<= 1) bsum += __shfl_xor(bsum, o, 64);
    int nanany = __any(nanloc);
    if (!nanany) { bce_out = -(bsum / (float)NN); vld_out = 1; }
  }

  if (lane == 0) {
    if (vld_out) { atomicAdd(&gred[0], bce_out); atomicAdd(&gred[1], 1.f); }
    __threadfence();
    int old = atomicAdd((int*)gred + 2, 1);
    if (old == BB * CC - 1) {
      float s = atomicAdd(&gred[0], 0.f);
      float n2 = atomicAdd(&gred[1], 0.f);
      out[0] = s / (n2 + 0.0001f);
    }
  }
}

extern "C" void kernel_launch(void* const* d_in, const int* in_sizes, int n_in,
                              void* d_out, int out_size, void* d_ws, size_t ws_size,
                              hipStream_t stream) {
  (void)in_sizes; (void)n_in; (void)out_size; (void)ws_size;
  const float* query = (const float*)d_in[0];
  const float* score = (const float*)d_in[1];
  const int*   label = (const int*)d_in[2];
  const int*   gt    = (const int*)d_in[3];
  const float* wts   = (const float*)d_in[4];
  float* ws = (float*)d_ws;

  size_t off = 0;
  int* cls = (int*)(ws + off);            off += (size_t)BB * MM;
  float* sm = ws + off;                   off += (size_t)BB * MM;
  int* valid = (int*)(ws + off);          off += (size_t)BB * CC;
  float* totalsum = ws + off;             off += (size_t)BB * DD;
  unsigned short* q0hh = (unsigned short*)(ws + off);  off += (size_t)NN * DD / 2;
  unsigned short* q0hl = (unsigned short*)(ws + off);  off += (size_t)NN * DD / 2;
  unsigned short* phh = (unsigned short*)(ws + off);   off += (size_t)BB * CC * KP * DD / 2;
  unsigned short* phl = (unsigned short*)(ws + off);   off += (size_t)BB * CC * KP * DD / 2;
  float* P = ws + off;                    off += (size_t)NCOL * NN;   // 8 MB
  float* gred = ws + off;                 off += 16;
  float* zbuf = ws + off;                 off += 1024;

  k_prep<<<BB + NQ0B + NTSB, 512, 0, stream>>>(score, query, label, cls, sm, valid,
                                               totalsum, q0hh, q0hl, gred, zbuf);
  k_gram<<<BB * CC, 512, 0, stream>>>(query, cls, valid, sm, totalsum, zbuf, phh, phl);
  dim3 gg((NN + 63) / 64, NCOL / 64);
  k_gemm<<<gg, 64, 0, stream>>>(q0hh, q0hl, phh, phl, P);
  k_sink<<<BB * CC, 64, 0, stream>>>(P, valid, gt, wts, gred, (float*)d_out);
}

// Round 10
// 258.189 us; speedup vs baseline: 1.0967x; 1.0967x over previous
//
#include <hip/hip_runtime.h>
#include <cmath>

#define BB 32     // batch
#define NN 784    // full points (28*28)
#define MM 392    // downsampled points (::2)
#define DD 1024   // feature dim
#define CC 20     // classes
#define JJ 3      // k-means centroids per class (K-1)
#define KP 4      // protos per class (3 centroids + backbone)
#define KM_ITERS 10
#define GMAX 64   // max members per (b,c); binomial(392,1/20) => P(>64) ~ 1e-16
#define NCOL (BB * CC * KP)   // 2560 proto columns
#define NQ0B 98   // q0h blocks (8 rows each, 784 rows)
#define NTSB (BB * 16)        // totalsum blocks

typedef __attribute__((ext_vector_type(8))) short bf16x8;
typedef __attribute__((ext_vector_type(4))) float f32x4;

// ---- bf16 split helpers (RTN-even) ----
__device__ inline unsigned short f2bf(float x) {
  unsigned int u = __float_as_uint(x);
  u += 0x7FFFu + ((u >> 16) & 1u);
  return (unsigned short)(u >> 16);
}
__device__ inline float bf2f(unsigned short h) {
  return __uint_as_float(((unsigned int)h) << 16);
}
__device__ inline void f2bf2(float x, unsigned short& hi, unsigned short& lo) {
  hi = f2bf(x);
  lo = f2bf(x - bf2f(hi));
}
__device__ inline void store_bf4(unsigned short* baseh, unsigned short* basel,
                                 int idx4, float4 v) {
  ushort4 h, l;
  f2bf2(v.x, h.x, l.x); f2bf2(v.y, h.y, l.y);
  f2bf2(v.z, h.z, l.z); f2bf2(v.w, h.w, l.w);
  ((ushort4*)baseh)[idx4] = h;
  ((ushort4*)basel)[idx4] = l;
}

// ---------- fused prep: heterogeneous grid ----------
__global__ __launch_bounds__(512) void k_prep(
    const float* __restrict__ score, const float* __restrict__ query,
    const int* __restrict__ label,
    int* __restrict__ cls, float* __restrict__ sm, int* __restrict__ valid,
    float* __restrict__ totalsum,
    unsigned short* __restrict__ q0hh, unsigned short* __restrict__ q0hl,
    float* __restrict__ gred) {
  int blk = blockIdx.x;
  int tid = threadIdx.x, lane = tid & 63, wv = tid >> 6;
  __shared__ int s_cnt[CC];
  __shared__ float sa[8][64];

  if (blk < BB) {
    int b = blk;
    if (tid < CC) s_cnt[tid] = 0;
    __syncthreads();
    if (tid < MM) {
      const float4* s4 = (const float4*)(score + ((size_t)b * NN + 2 * tid) * CC);
      float4 r[5];
      #pragma unroll
      for (int k = 0; k < 5; k++) r[k] = s4[k];
      const float* s = (const float*)r;
      float best = s[0]; int bi = 0; float acc = s[0];
      #pragma unroll
      for (int c = 1; c < CC; c++) { float v = s[c]; acc += v; if (v > best) { best = v; bi = c; } }
      cls[b * MM + tid] = bi;
      sm[b * MM + tid] = acc / (float)CC;
      atomicAdd(&s_cnt[bi], 1);
    }
    __syncthreads();
    if (tid < CC) {
      int cv = s_cnt[tid];
      valid[b * CC + tid] = (label[b * CC + tid] > 0 && cv >= KP) ? 1 : 0;
    }
    if (blk == 0 && tid == 0) { gred[0] = 0.f; gred[1] = 0.f; ((int*)gred)[2] = 0; }
  } else if (blk < BB + NQ0B) {
    int n = (blk - BB) * 8 + wv;             // 0..783
    const float* src = query + (size_t)n * DD;
    float v[16];
    float ss = 0.f;
    #pragma unroll
    for (int j = 0; j < 16; j++) { v[j] = src[lane + 64 * j]; ss += v[j] * v[j]; }
    #pragma unroll
    for (int o = 32; o > 0; o >>= 1) ss += __shfl_xor(ss, o, 64);
    float nrm = fmaxf(sqrtf(ss), 1e-12f);
    #pragma unroll
    for (int j = 0; j < 16; j++) {
      unsigned short hi, lo;
      f2bf2(v[j] / nrm, hi, lo);
      q0hh[(size_t)n * DD + lane + 64 * j] = hi;
      q0hl[(size_t)n * DD + lane + 64 * j] = lo;
    }
  } else {
    int t = blk - BB - NQ0B;                 // 0..511
    int b = t >> 4, ch = t & 15;
    const float* qb = query + (size_t)b * NN * DD + ch * 64 + lane;
    float a = 0.f;
    #pragma unroll 7
    for (int r = 0; r < 49; r++) {
      int i = wv * 49 + r;
      a += qb[(size_t)(2 * i) * DD];         // coalesced 256B per row
    }
    sa[wv][lane] = a;
    __syncthreads();
    if (wv == 0) {
      float s = 0.f;
      #pragma unroll
      for (int w = 0; w < 8; w++) s += sa[w][lane];
      totalsum[(size_t)b * DD + ch * 64 + lane] = s;
    }
  }
}

// ---------- fused (valid blocks only): membership + MFMA-Gram + k-means + centroids+backbone ----------
// R8-exact: Gram G = X X^T via split-bf16 MFMA from LDS-staged bf16 hi/lo (conversion done ONCE
// per element during staging — R9's per-consumer in-loop cvt was ~12x more VALU and regressed).
__global__ __launch_bounds__(512) void k_gram(
    const float* __restrict__ query, const int* __restrict__ cls,
    const int* __restrict__ valid, const float* __restrict__ sm,
    const float* __restrict__ totalsum,
    unsigned short* __restrict__ phh, unsigned short* __restrict__ phl) {
  int bc = blockIdx.x;
  if (!valid[bc]) return;              // invalid pairs: no work at all
  int b = bc / CC, c = bc - b * CC;
  int tid = threadIdx.x, lane = tid & 63, wv = tid >> 6;
  const float* qb = query + (size_t)b * NN * DD;
  __shared__ int s_wtot[8];
  __shared__ int s_list[GMAX];
  __shared__ __align__(16) unsigned short Xh[GMAX][136];  // 17.4 KB (stride 272B, 16B-aligned)
  __shared__ __align__(16) unsigned short Xl[GMAX][136];  // 17.4 KB
  __shared__ float Gl[GMAX][65];                          // 16.6 KB Gram
  __shared__ float s_w[JJ][GMAX];
  __shared__ int s_rank[JJ];
  __shared__ float s_red2[8];

  // ---- membership via ballot scan (stable ascending i), 2 barriers
  int flag = 0;
  if (tid < MM) flag = (cls[b * MM + tid] == c) ? 1 : 0;
  unsigned long long msk = __ballot(flag);
  int wp = __popcll(msk & ((1ull << lane) - 1ull));
  if (lane == 0) s_wtot[wv] = __popcll(msk);
  __syncthreads();
  int off = 0, mtot = 0;
  #pragma unroll
  for (int w = 0; w < 8; w++) { int t = s_wtot[w]; if (w < wv) off += t; mtot += t; }
  int mc = mtot > GMAX ? GMAX : mtot;
  if (flag) { int pos = off + wp; if (pos < GMAX) s_list[pos] = tid; }
  __syncthreads();

  int T16 = (mc + 15) >> 4;            // 16-row tiles covering mc
  int ntile16 = T16 * (T16 + 1) / 2;   // <= 10 upper-triangle G tiles

  // ---- zero bf16 rows [mc, 16*T16): padding contributes 0 to MFMA
  int zrows = 16 * T16 - mc;
  for (int z = tid; z < zrows * 34; z += 512) {
    int zr = mc + z / 34, zc = (z % 34) * 4;
    ushort4 zz = {0, 0, 0, 0};
    *(ushort4*)&Xh[zr][zc] = zz;
    *(ushort4*)&Xl[zr][zc] = zz;
  }

  // ---- per-thread staging slots: element e = (row = e>>5, f = e&31) of mc*32 float4s
  const float* pb[4] = {nullptr, nullptr, nullptr, nullptr};
  unsigned short* xdh[4]; unsigned short* xdl[4];
  #pragma unroll
  for (int s = 0; s < 4; s++) {
    int e = tid + s * 512;
    if (e < mc * 32) {
      int row = e >> 5, f = e & 31;
      pb[s] = qb + (size_t)(2 * s_list[row]) * DD + f * 4;
      xdh[s] = &Xh[row][f * 4];
      xdl[s] = &Xl[row][f * 4];
    }
  }

  // ---- this wave's G tiles (t = wv, wv+8), triangle map
  int ti0 = -1, tj0 = 0, ti1 = -1, tj1 = 0;
  if (wv < ntile16) {
    int t = wv, i = 0;
    while ((i + 1) * (i + 2) / 2 <= t) i++;
    ti0 = i; tj0 = t - i * (i + 1) / 2;
  }
  if (wv + 8 < ntile16) {
    int t = wv + 8, i = 0;
    while ((i + 1) * (i + 2) / 2 <= t) i++;
    ti1 = i; tj1 = t - i * (i + 1) / 2;
  }
  f32x4 acc0 = (f32x4){0.f, 0.f, 0.f, 0.f};
  f32x4 acc1 = (f32x4){0.f, 0.f, 0.f, 0.f};
  int fr = lane & 15, fk = (lane >> 4) * 8;   // MFMA A/B fragment: row fr, k-offset fk

  // ---- staged sweep, 8 chunks of 128 cols, 1-ahead prefetch, convert-to-bf16 in-register
  float4 cur[4], nxt[4];
  #pragma unroll
  for (int s = 0; s < 4; s++) {
    cur[s] = make_float4(0.f, 0.f, 0.f, 0.f);
    nxt[s] = make_float4(0.f, 0.f, 0.f, 0.f);
    if (pb[s]) cur[s] = *(const float4*)(pb[s]);
  }
  for (int ch = 0; ch < 8; ch++) {
    __syncthreads();                   // previous chunk's MFMA reads done
    #pragma unroll
    for (int s = 0; s < 4; s++) {
      if (pb[s]) {
        ushort4 h, l;
        f2bf2(cur[s].x, h.x, l.x); f2bf2(cur[s].y, h.y, l.y);
        f2bf2(cur[s].z, h.z, l.z); f2bf2(cur[s].w, h.w, l.w);
        *(ushort4*)xdh[s] = h;
        *(ushort4*)xdl[s] = l;
      }
    }
    if (ch < 7) {                      // in flight during compute
      #pragma unroll
      for (int s = 0; s < 4; s++) if (pb[s]) nxt[s] = *(const float4*)(pb[s] + (ch + 1) * 128);
    }
    __syncthreads();                   // staging visible
    if (ti0 >= 0) {
      const unsigned short* pah = &Xh[16 * ti0 + fr][fk];
      const unsigned short* pal = &Xl[16 * ti0 + fr][fk];
      const unsigned short* pbh = &Xh[16 * tj0 + fr][fk];
      const unsigned short* pbl = &Xl[16 * tj0 + fr][fk];
      #pragma unroll
      for (int ks = 0; ks < 4; ks++) {
        bf16x8 ah = *(const bf16x8*)(pah + 32 * ks);
        bf16x8 al = *(const bf16x8*)(pal + 32 * ks);
        bf16x8 bh = *(const bf16x8*)(pbh + 32 * ks);
        bf16x8 bl = *(const bf16x8*)(pbl + 32 * ks);
        acc0 = __builtin_amdgcn_mfma_f32_16x16x32_bf16(ah, bh, acc0, 0, 0, 0);
        acc0 = __builtin_amdgcn_mfma_f32_16x16x32_bf16(ah, bl, acc0, 0, 0, 0);
        acc0 = __builtin_amdgcn_mfma_f32_16x16x32_bf16(al, bh, acc0, 0, 0, 0);
      }
    }
    if (ti1 >= 0) {
      const unsigned short* pah = &Xh[16 * ti1 + fr][fk];
      const unsigned short* pal = &Xl[16 * ti1 + fr][fk];
      const unsigned short* pbh = &Xh[16 * tj1 + fr][fk];
      const unsigned short* pbl = &Xl[16 * tj1 + fr][fk];
      #pragma unroll
      for (int ks = 0; ks < 4; ks++) {
        bf16x8 ah = *(const bf16x8*)(pah + 32 * ks);
        bf16x8 al = *(const bf16x8*)(pal + 32 * ks);
        bf16x8 bh = *(const bf16x8*)(pbh + 32 * ks);
        bf16x8 bl = *(const bf16x8*)(pbl + 32 * ks);
        acc1 = __builtin_amdgcn_mfma_f32_16x16x32_bf16(ah, bh, acc1, 0, 0, 0);
        acc1 = __builtin_amdgcn_mfma_f32_16x16x32_bf16(ah, bl, acc1, 0, 0, 0);
        acc1 = __builtin_amdgcn_mfma_f32_16x16x32_bf16(al, bh, acc1, 0, 0, 0);
      }
    }
    #pragma unroll
    for (int s = 0; s < 4; s++) cur[s] = nxt[s];
  }

  // ---- write G tiles (C/D layout: col=lane&15, row=(lane>>4)*4+reg) + symmetric mirror
  if (ti0 >= 0) {
    #pragma unroll
    for (int r = 0; r < 4; r++) {
      int gr = 16 * ti0 + (lane >> 4) * 4 + r;
      int gc = 16 * tj0 + fr;
      Gl[gr][gc] = acc0[r]; Gl[gc][gr] = acc0[r];
    }
  }
  if (ti1 >= 0) {
    #pragma unroll
    for (int r = 0; r < 4; r++) {
      int gr = 16 * ti1 + (lane >> 4) * 4 + r;
      int gc = 16 * tj1 + fr;
      Gl[gr][gc] = acc1[r]; Gl[gc][gr] = acc1[r];
    }
  }
  __syncthreads();

  // ---- Gram-space k-means: wave 0 only (in-wave LDS ordering; no barriers needed)
  if (wv == 0) {
    bool act = lane < mc;
    float smv = act ? sm[b * MM + s_list[lane]] : 0.f;
    s_w[0][lane] = (lane == 0) ? 1.f : 0.f;
    s_w[1][lane] = (lane == 1) ? 1.f : 0.f;
    s_w[2][lane] = (lane == 2) ? 1.f : 0.f;
    int aj = 0, n0 = 0, n1 = 0, n2 = 0;
    for (int it = 0; it <= KM_ITERS; it++) {
      float h0 = 0.f, h1 = 0.f, h2 = 0.f;
      if (act) {
        for (int i = 0; i < mc; i++) {
          float g = Gl[lane][i];
          h0 += s_w[0][i] * g; h1 += s_w[1][i] * g; h2 += s_w[2][i] * g;
        }
      }
      float t0 = s_w[0][lane] * h0, t1 = s_w[1][lane] * h1, t2 = s_w[2][lane] * h2;
      for (int o = 1; o < 64; o <<= 1) {
        t0 += __shfl_xor(t0, o, 64); t1 += __shfl_xor(t1, o, 64); t2 += __shfl_xor(t2, o, 64);
      }
      float e0 = t0 - 2.f * h0, e1 = t1 - 2.f * h1, e2 = t2 - 2.f * h2;
      aj = 0; float bv = e0;
      if (e1 < bv) { bv = e1; aj = 1; }
      if (e2 < bv) { bv = e2; aj = 2; }
      n0 = __popcll(__ballot(act && aj == 0));
      n1 = __popcll(__ballot(act && aj == 1));
      n2 = __popcll(__ballot(act && aj == 2));
      if (it == KM_ITERS) break;
      if (act) {                           // empty cluster keeps old w
        if (n0 > 0) s_w[0][lane] = (aj == 0) ? 1.f / (float)n0 : 0.f;
        if (n1 > 0) s_w[1][lane] = (aj == 1) ? 1.f / (float)n1 : 0.f;
        if (n2 > 0) s_w[2][lane] = (aj == 2) ? 1.f / (float)n2 : 0.f;
      }
    }
    float s0 = (act && aj == 0) ? smv : 0.f;
    float s1 = (act && aj == 1) ? smv : 0.f;
    float s2 = (act && aj == 2) ? smv : 0.f;
    for (int o = 1; o < 64; o <<= 1) {
      s0 += __shfl_xor(s0, o, 64); s1 += __shfl_xor(s1, o, 64); s2 += __shfl_xor(s2, o, 64);
    }
    if (lane == 0) {
      float avg[JJ];
      avg[0] = (n0 > 0) ? s0 / (float)n0 : -INFINITY;
      avg[1] = (n1 > 0) ? s1 / (float)n1 : -INFINITY;
      avg[2] = (n2 > 0) ? s2 / (float)n2 : -INFINITY;
      bool used[JJ] = {false, false, false};
      for (int s = 0; s < JJ; s++) {       // stable argsort descending
        int bi = -1; float bv = 0.f;
        for (int j = 0; j < JJ; j++)
          if (!used[j] && (bi < 0 || avg[j] > bv)) { bi = j; bv = avg[j]; }
        used[bi] = true; s_rank[bi] = s;   // rank of original cluster bi
      }
    }
  }
  __syncthreads();

  // ---- epilogue: 4 groups x 128 threads; j<3 = centroid j, j==3 = backbone.
  float4 a0 = make_float4(0.f, 0.f, 0.f, 0.f), a1 = make_float4(0.f, 0.f, 0.f, 0.f);
  int j = tid >> 7, q = tid & 127;
  if (j < 3) {
    for (int g = 0; g < mc; g++) {
      float w = s_w[j][g];                 // wave-uniform broadcast
      if (w != 0.f) {                      // wave-coherent branch
        const float4* row = (const float4*)(qb + (size_t)(2 * s_list[g]) * DD);
        float4 v0 = row[q], v1 = row[q + 128];
        a0.x += w * v0.x; a0.y += w * v0.y; a0.z += w * v0.z; a0.w += w * v0.w;
        a1.x += w * v1.x; a1.y += w * v1.y; a1.z += w * v1.z; a1.w += w * v1.w;
      }
    }
  } else {
    for (int g = 0; g < mc; g++) {
      const float4* row = (const float4*)(qb + (size_t)(2 * s_list[g]) * DD);
      float4 v0 = row[q], v1 = row[q + 128];
      a0.x += v0.x; a0.y += v0.y; a0.z += v0.z; a0.w += v0.w;
      a1.x += v1.x; a1.y += v1.y; a1.z += v1.z; a1.w += v1.w;
    }
    const float4* tb = (const float4*)(totalsum + (size_t)b * DD);
    float4 t0 = tb[q], t1 = tb[q + 128];
    float denom = fmaxf((float)(MM - mtot), 1.f);
    float inv = 1.f / denom;
    a0.x = (t0.x - a0.x) * inv; a0.y = (t0.y - a0.y) * inv;
    a0.z = (t0.z - a0.z) * inv; a0.w = (t0.w - a0.w) * inv;
    a1.x = (t1.x - a1.x) * inv; a1.y = (t1.y - a1.y) * inv;
    a1.z = (t1.z - a1.z) * inv; a1.w = (t1.w - a1.w) * inv;
  }
  float ssq = a0.x * a0.x + a0.y * a0.y + a0.z * a0.z + a0.w * a0.w
            + a1.x * a1.x + a1.y * a1.y + a1.z * a1.z + a1.w * a1.w;
  #pragma unroll
  for (int o = 1; o < 64; o <<= 1) ssq += __shfl_xor(ssq, o, 64);
  if (lane == 0) s_red2[wv] = ssq;
  __syncthreads();
  float nrm = fmaxf(sqrtf(s_red2[2 * j] + s_red2[2 * j + 1]), 1e-12f);
  int prow = (j < 3) ? s_rank[j] : 3;
  size_t rowoff = ((size_t)bc * KP + prow) * DD;
  float4 o0 = make_float4(a0.x / nrm, a0.y / nrm, a0.z / nrm, a0.w / nrm);
  float4 o1 = make_float4(a1.x / nrm, a1.y / nrm, a1.z / nrm, a1.w / nrm);
  store_bf4(phh + rowoff, phl + rowoff, q, o0);
  store_bf4(phh + rowoff, phl + rowoff, q + 128, o1);
}

// ---------- sim GEMM via bf16 split MFMA; 1 wave/block, 64x64 tile, no LDS, no barriers ----------
__global__ __launch_bounds__(64) void k_gemm(
    const unsigned short* __restrict__ Ah, const unsigned short* __restrict__ Al,
    const unsigned short* __restrict__ Bh, const unsigned short* __restrict__ Bl,
    float* __restrict__ P) {
  int n0 = blockIdx.y * 64;
  int m0 = blockIdx.x * 64;
  int lane = threadIdx.x;
  int kh = lane >> 4;                    // 0..3
  int lr = lane & 15;

  const unsigned short* pa_h[4]; const unsigned short* pa_l[4];
  #pragma unroll
  for (int mi = 0; mi < 4; mi++) {
    size_t o = (size_t)(m0 + mi * 16 + lr) * DD + kh * 8;   // OOB m-rows read adjacent ws (harmless, unstored)
    pa_h[mi] = Ah + o; pa_l[mi] = Al + o;
  }
  const unsigned short* pb_h[4]; const unsigned short* pb_l[4];
  #pragma unroll
  for (int ni = 0; ni < 4; ni++) {
    int col = n0 + ni * 16 + lr;         // B row == col (ph rows are [bc*KP+proto] = col order)
    size_t o = (size_t)col * DD + kh * 8;
    pb_h[ni] = Bh + o; pb_l[ni] = Bl + o;
  }

  f32x4 acc[4][4];
  #pragma unroll
  for (int mi = 0; mi < 4; mi++)
    #pragma unroll
    for (int ni = 0; ni < 4; ni++) acc[mi][ni] = (f32x4){0.f, 0.f, 0.f, 0.f};

  for (int k0 = 0; k0 < DD; k0 += 32) {
    bf16x8 ah[4], al[4], bh[4], bl[4];
    #pragma unroll
    for (int i = 0; i < 4; i++) {
      ah[i] = *(const bf16x8*)(pa_h[i] + k0);
      al[i] = *(const bf16x8*)(pa_l[i] + k0);
      bh[i] = *(const bf16x8*)(pb_h[i] + k0);
      bl[i] = *(const bf16x8*)(pb_l[i] + k0);
    }
    #pragma unroll
    for (int mi = 0; mi < 4; mi++)
      #pragma unroll
      for (int ni = 0; ni < 4; ni++) {
        acc[mi][ni] = __builtin_amdgcn_mfma_f32_16x16x32_bf16(ah[mi], bh[ni], acc[mi][ni], 0, 0, 0);
        acc[mi][ni] = __builtin_amdgcn_mfma_f32_16x16x32_bf16(ah[mi], bl[ni], acc[mi][ni], 0, 0, 0);
        acc[mi][ni] = __builtin_amdgcn_mfma_f32_16x16x32_bf16(al[mi], bh[ni], acc[mi][ni], 0, 0, 0);
      }
  }

  // C/D layout: col = lane&15, row = (lane>>4)*4 + reg  -> float4 contiguous in m
  #pragma unroll
  for (int ni = 0; ni < 4; ni++) {
    int col = n0 + ni * 16 + lr;
    #pragma unroll
    for (int mi = 0; mi < 4; mi++) {
      int m = m0 + mi * 16 + kh * 4;
      if (m < NN) {
        *(f32x4*)(P + (size_t)col * NN + m) = acc[mi][ni];
      }
    }
  }
}

// ---------- Sinkhorn + BCE: ONE WAVE per (b,c); no LDS, no barriers, per-wave early exit ----------
// Divisions in the iteration replaced with v_rcp_f32 (1-ulp approx): Sinkhorn is a self-
// correcting fixed point and the 0.01 convergence threshold is 5 orders above the error.
__global__ __launch_bounds__(256) void k_sink(const float* __restrict__ P,
    const int* __restrict__ valid, const int* __restrict__ gt,
    const float* __restrict__ wts, float* __restrict__ gred, float* __restrict__ out) {
  int wv = threadIdx.x >> 6, lane = threadIdx.x & 63;
  int bc = blockIdx.x * 4 + wv;
  int b = bc / CC, c = bc - b * CC;
  float bce_out = 0.f; int vld_out = 0;

  if (valid[bc]) {                         // wave-uniform
    float4 kv[13]; float rr[13];
    #pragma unroll
    for (int s = 0; s < 13; s++) {
      int n = lane + 64 * s;
      kv[s] = make_float4(0.f, 0.f, 0.f, 0.f); rr[s] = 1.f;
      if (n < NN) {
        float4 o;
        o.x = expf(-(1.0f - P[((size_t)(4 * bc + 0)) * NN + n]) / 0.1f);
        o.y = expf(-(1.0f - P[((size_t)(4 * bc + 1)) * NN + n]) / 0.1f);
        o.z = expf(-(1.0f - P[((size_t)(4 * bc + 2)) * NN + n]) / 0.1f);
        o.w = expf(-(1.0f - P[((size_t)(4 * bc + 3)) * NN + n]) / 0.1f);
        kv[s] = o;
      }
    }
    const float uu = 1.0f / (float)NN, vv = 1.0f / (float)KP;
    float c0 = 1.f, c1 = 1.f, c2 = 1.f, c3 = 1.f;
    for (int it = 0; it < 100; it++) {
      float dsum = 0.f, p0 = 0.f, p1 = 0.f, p2 = 0.f, p3 = 0.f;
      #pragma unroll
      for (int s = 0; s < 13; s++) {
        int n = lane + 64 * s;
        if (n < NN) {
          float4 k4 = kv[s];
          float S = k4.x * c0 + k4.y * c1 + k4.z * c2 + k4.w * c3;
          float r1 = uu * __builtin_amdgcn_rcpf(S);
          dsum += fabsf(r1 - rr[s]);
          rr[s] = r1;
          p0 += k4.x * r1; p1 += k4.y * r1; p2 += k4.z * r1; p3 += k4.w * r1;
        }
      }
      #pragma unroll
      for (int o = 1; o < 64; o <<= 1) {
        dsum += __shfl_xor(dsum, o, 64);
        p0 += __shfl_xor(p0, o, 64); p1 += __shfl_xor(p1, o, 64);
        p2 += __shfl_xor(p2, o, 64); p3 += __shfl_xor(p3, o, 64);
      }
      c0 = vv * __builtin_amdgcn_rcpf(p0);
      c1 = vv * __builtin_amdgcn_rcpf(p1);
      c2 = vv * __builtin_amdgcn_rcpf(p2);
      c3 = vv * __builtin_amdgcn_rcpf(p3);
      if (dsum / (float)NN < 0.01f) break;   // wave-uniform
    }
    float w0 = wts[0], w1 = wts[1], w2 = wts[2], w3 = wts[3];
    float bsum = 0.f; int nanloc = 0;
    const int* gtb = gt + b * NN;
    #pragma unroll
    for (int s = 0; s < 13; s++) {
      int n = lane + 64 * s;
      if (n < NN) {
        float4 k4 = kv[s];
        float rv = rr[s];
        float T0 = rv * c0 * k4.x, T1 = rv * c1 * k4.y, T2 = rv * c2 * k4.z, T3 = rv * c3 * k4.w;
        if (T0 != T0 || T1 != T1 || T2 != T2 || T3 != T3) nanloc = 1;
        float pred = T0 * w0 + T1 * w1 + T2 * w2 + T3 * w3;
        float pcl = fminf(fmaxf(pred, 0.f), 1.f);
        float t = (gtb[n] == c + 1) ? fmaxf(logf(pcl), -100.f) : fmaxf(logf(1.f - pcl), -100.f);
        bsum += t;
      }
    }
    #pragma unroll
    for (int o = 1; o < 64; o <<= 1) bsum += __shfl_xor(bsum, o, 64);
    int nanany = __any(nanloc);
    if (!nanany) { bce_out = -(bsum / (float)NN); vld_out = 1; }
  }

  if (lane == 0) {
    if (vld_out) { atomicAdd(&gred[0], bce_out); atomicAdd(&gred[1], 1.f); }
    __threadfence();
    int old = atomicAdd((int*)gred + 2, 1);
    if (old == BB * CC - 1) {
      float s = atomicAdd(&gred[0], 0.f);
      float n2 = atomicAdd(&gred[1], 0.f);
      out[0] = s / (n2 + 0.0001f);
    }
  }
}

extern "C" void kernel_launch(void* const* d_in, const int* in_sizes, int n_in,
                              void* d_out, int out_size, void* d_ws, size_t ws_size,
                              hipStream_t stream) {
  (void)in_sizes; (void)n_in; (void)out_size; (void)ws_size;
  const float* query = (const float*)d_in[0];
  const float* score = (const float*)d_in[1];
  const int*   label = (const int*)d_in[2];
  const int*   gt    = (const int*)d_in[3];
  const float* wts   = (const float*)d_in[4];
  float* ws = (float*)d_ws;

  size_t off = 0;
  int* cls = (int*)(ws + off);            off += (size_t)BB * MM;
  float* sm = ws + off;                   off += (size_t)BB * MM;
  int* valid = (int*)(ws + off);          off += (size_t)BB * CC;
  float* totalsum = ws + off;             off += (size_t)BB * DD;
  unsigned short* q0hh = (unsigned short*)(ws + off);  off += (size_t)NN * DD / 2;
  unsigned short* q0hl = (unsigned short*)(ws + off);  off += (size_t)NN * DD / 2;
  unsigned short* phh = (unsigned short*)(ws + off);   off += (size_t)BB * CC * KP * DD / 2;
  unsigned short* phl = (unsigned short*)(ws + off);   off += (size_t)BB * CC * KP * DD / 2;
  float* P = ws + off;                    off += (size_t)NCOL * NN;   // 8 MB
  float* gred = ws + off;                 off += 16;

  k_prep<<<BB + NQ0B + NTSB, 512, 0, stream>>>(score, query, label, cls, sm, valid,
                                               totalsum, q0hh, q0hl, gred);
  k_gram<<<BB * CC, 512, 0, stream>>>(query, cls, valid, sm, totalsum, phh, phl);
  dim3 gg((NN + 63) / 64, NCOL / 64);
  k_gemm<<<gg, 64, 0, stream>>>(q0hh, q0hl, phh, phl, P);
  k_sink<<<BB * CC / 4, 256, 0, stream>>>(P, valid, gt, wts, gred, (float*)d_out);
}